// Round 3
// baseline (286.157 us; speedup 1.0000x reference)
//
#include <hip/hip_runtime.h>

typedef __fp16 h2 __attribute__((ext_vector_type(2)));
typedef __fp16 h8 __attribute__((ext_vector_type(8)));
typedef float f4 __attribute__((ext_vector_type(4)));

namespace {
constexpr int JSTR = 72;         // halves per j-row (64 c + 8 pad) -> 144 B, breaks bank aliasing
constexpr int JN = 48;           // j rows; j<4 and j>=36 are permanent zero halo
constexpr int COLH = JN * JSTR;  // 3456 halves = 6912 B per column buffer
}

// 512 threads = 8 waves: (wv&3) = D-tile decomposition, (wv>>2) = position group.
// Each block serves FOUR w positions (w0..w0+3) from one staged column stream:
// per-column staging/sync cost amortized 2x vs the 2-position version, at equal
// occupancy (512 blocks x 512 thr = 2 blocks/CU = 4 waves/SIMD, same as before).
__global__ __launch_bounds__(512, 4) void corr3d_mfma(
    const float* __restrict__ in1, const float* __restrict__ in2,
    float* __restrict__ out)
{
  __shared__ __align__(16) __fp16 colbuf[2][COLH];  // 13824 B, double-buffered in2 column
  __shared__ __align__(16) float obuf[4 * 9 * 32];  // [pos][dz][d] band reorg, 4608 B

  const int tid = threadIdx.x;
  // XCD-aware chunked swizzle: consecutive logical blocks share in2 columns;
  // give each of the 8 XCDs one contiguous 64-block slab. 512 % 8 == 0 -> bijective.
  const int blk = ((blockIdx.x & 7) << 6) | (blockIdx.x >> 3);
  const int b = blk >> 8;
  const int h = (blk >> 3) & 31;
  const int w0 = (blk & 7) << 2;  // four w positions: w0 .. w0+3

  const int lane = tid & 63;
  const int wv = tid >> 6;        // 0..7
  const int dwv = wv & 3;         // D-tile wave: (T0,s0),(T1,s0),(T1,s1),(T2,s1)
  const int posbase = (wv >> 2) << 1;  // 0 or 2: this wave's position pair
  const int jb = (dwv == 0) ? 0 : (dwv == 3) ? 32 : 16;  // A-tile j base
  const int db = (dwv >= 2) ? 16 : 0;                    // d-strip base
  const int l15 = lane & 15;
  const int lhi = lane >> 4;

  const float* in1b = in1 + ((size_t)b << 21);
  const float* in2b = in2 + ((size_t)b << 21);

  // zero halo rows of both column buffers (j<4, j>=36): written once, never touched again
  for (int i = tid; i < 1152; i += 512) {
    const int bu = i / 576;
    const int r = i - bu * 576;
    const int jrow = r / 36;
    const int cc = r - jrow * 36;
    const int j = (jrow < 4) ? jrow : jrow + 32;
    h2 z = {(__fp16)0.f, (__fp16)0.f};
    *(h2*)&colbuf[bu][j * JSTR + cc * 2] = z;
  }

  // staging role: d = tid&31 (coalesced), c-pair base = tid>>5 (0..15)
  const int sd = tid & 31;
  const int scq = tid >> 5;

  auto stage = [&](const float* src, bool valid, __fp16* dst) {
#pragma unroll
    for (int it = 0; it < 2; ++it) {
      const int cp = scq + (it << 4);  // c-pair 0..31
      h2 v = {(__fp16)0.f, (__fp16)0.f};
      if (valid) {
        const float x = src[((size_t)(2 * cp) << 15) + sd];
        const float y = src[((size_t)(2 * cp + 1) << 15) + sd];
        v = __builtin_amdgcn_cvt_pkrtz(x, y);
      }
      *(h2*)&dst[(4 + sd) * JSTR + 2 * cp] = v;  // [j=4+d][c] layout
    }
  };

  // ---- prologue: in1 B-operand fragments. Stage each of the 4 positions block-wide;
  // the owning position-group reads its fragment (static bfr indices only — rule #20).
  h8 bfr[2][2];
#pragma unroll
  for (int pos = 0; pos < 4; ++pos) {
    __syncthreads();
    stage(in1b + (h << 10) + ((w0 + pos) << 5), true, colbuf[0]);
    __syncthreads();
    if (pos == posbase) {
#pragma unroll
      for (int ch = 0; ch < 2; ++ch)
        bfr[0][ch] = *(const h8*)&colbuf[0][(4 + db + l15) * JSTR + ch * 32 + (lhi << 3)];
    } else if (pos == posbase + 1) {
#pragma unroll
      for (int ch = 0; ch < 2; ++ch)
        bfr[1][ch] = *(const h8*)&colbuf[0][(4 + db + l15) * JSTR + ch * 32 + (lhi << 3)];
    }
  }
  __syncthreads();
  // stage in2 column 0 into buf 0
  {
    const int hp = h - 4, wp = w0 - 4;
    const bool valid = ((unsigned)hp < 32u) && ((unsigned)wp < 32u);
    stage(in2b + (hp << 10) + (wp << 5), valid, colbuf[0]);
  }
  __syncthreads();

  // band-write targets per (lane, reg): m=(lhi*4+r), n=l15; j=jb+m, d=db+n, dz=j-d
  int boff[4];
  unsigned bmask = 0;
#pragma unroll
  for (int r = 0; r < 4; ++r) {
    const int m = (lhi << 2) + r;
    const int dz = jb + m - db - l15;
    if ((unsigned)dz < 9u) bmask |= 1u << r;
    boff[r] = dz * 32 + db + l15;
  }

  // ---- main loop over 108 columns (hc 0..8, wc 0..11)
  for (int ci = 0; ci < 108; ++ci) {
    if (ci + 1 < 108) {  // stage next column into the other buffer
      const int cn = ci + 1;
      const int hcn = cn / 12;
      const int wcn = cn - hcn * 12;
      const int hp = h - 4 + hcn;
      const int wp = w0 - 4 + wcn;
      const bool valid = ((unsigned)hp < 32u) && ((unsigned)wp < 32u);
      stage(in2b + (hp << 10) + (wp << 5), valid, colbuf[cn & 1]);
    }
    const int hc = ci / 12;
    const int wc = ci - hc * 12;

    const __fp16* cb = colbuf[ci & 1];
    const h8 a0 = *(const h8*)&cb[(jb + l15) * JSTR + (lhi << 3)];
    const h8 a1 = *(const h8*)&cb[(jb + l15) * JSTR + 32 + (lhi << 3)];
#pragma unroll
    for (int pp = 0; pp < 2; ++pp) {
      const int pos = posbase + pp;  // dx = wc - pos must be in [0,9)
      if (wc >= pos && wc - pos <= 8) {
        f4 acc = {0.f, 0.f, 0.f, 0.f};
        acc = __builtin_amdgcn_mfma_f32_16x16x32_f16(a0, bfr[pp][0], acc, 0, 0, 0);
        acc = __builtin_amdgcn_mfma_f32_16x16x32_f16(a1, bfr[pp][1], acc, 0, 0, 0);
#pragma unroll
        for (int r = 0; r < 4; ++r)
          if (bmask & (1u << r)) obuf[pos * 288 + boff[r]] = acc[r];
      }
    }
    __syncthreads();  // band writes visible
    // readback [pos][dz][d] rows -> coalesced float4 nontemporal global stores
    if (tid < 288) {
      const int pos = tid / 72;  // 0..3
      const int rr = tid - pos * 72;
      const int dz = rr >> 3;
      const int q = rr & 7;
      if (wc >= pos && wc - pos <= 8) {
        const f4 v = *(const f4*)&obuf[pos * 288 + dz * 32 + (q << 2)];
        const size_t ch = (size_t)(b * 729 + (hc * 9 + (wc - pos)) * 9 + dz);
        f4* dstp = (f4*)(out + (ch << 15) + (h << 10) + ((w0 + pos) << 5) + (q << 2));
        __builtin_nontemporal_store(v, dstp);
      }
    }
    __syncthreads();  // obuf free for next column's band writes
  }
}

extern "C" void kernel_launch(void* const* d_in, const int* in_sizes, int n_in,
                              void* d_out, int out_size, void* d_ws, size_t ws_size,
                              hipStream_t stream) {
  const float* in1 = (const float*)d_in[0];
  const float* in2 = (const float*)d_in[1];
  float* out = (float*)d_out;
  corr3d_mfma<<<dim3(512), dim3(512), 0, stream>>>(in1, in2, out);
}

// Round 4
// 279.869 us; speedup vs baseline: 1.0225x; 1.0225x over previous
//
#include <hip/hip_runtime.h>

typedef __fp16 h2 __attribute__((ext_vector_type(2)));
typedef __fp16 h8 __attribute__((ext_vector_type(8)));
typedef float f4 __attribute__((ext_vector_type(4)));

namespace {
constexpr int JSTR = 72;         // halves per j-row (64 c + 8 pad) -> 144 B, breaks bank aliasing
constexpr int JN = 48;           // j rows; j<4 and j>=36 are permanent zero halo
constexpr int COLH = JN * JSTR;  // 3456 halves = 6912 B per column buffer
}

// 256 threads x 1024 blocks (4 blocks/CU = 4 independent barrier domains — R2
// showed 2x512 was worse than 4x256 at equal wave count: latency-bound, not
// volume-bound). ONE barrier per column:
//   1. issue next-column global loads -> regs        (T14 issue-early)
//   2. ds_read A-frags, MFMA column ci
//   3. band-write acc -> obuf[ci&1]                  (obuf double-buffered)
//   4. readback column ci-1 from obuf[(ci-1)&1] -> global NT stores
//   5. cvt + ds_write staged regs -> colbuf[(ci+1)&1] (T14 write-late; load
//      latency hidden under steps 2-4)
//   6. __syncthreads
// Hazard audit (all separated by exactly the one barrier):
//   colbuf[(ci+1)&1] write(5,ci)  vs read(2,ci+1)          -> barrier(ci)
//   colbuf[ci&1]     read(2,ci)   vs write(5,ci+1)         -> barrier(ci)
//   obuf[ci&1]       write(3,ci)  vs read(4,ci+1)          -> barrier(ci)
//   obuf[(ci-1)&1]   read(4,ci)   vs write(3,ci+1)         -> barrier(ci)
__global__ __launch_bounds__(256, 4) void corr3d_mfma(
    const float* __restrict__ in1, const float* __restrict__ in2,
    float* __restrict__ out)
{
  __shared__ __align__(16) __fp16 colbuf[2][COLH];   // 13824 B
  __shared__ __align__(16) float obuf[2][2 * 9 * 32];  // [parity][pos*288+dz*32+d], 4608 B

  const int tid = threadIdx.x;
  // XCD-aware chunked swizzle: blocks sharing in2 columns are consecutive
  // logical ids; give each of the 8 XCDs one contiguous 128-block slab.
  // 1024 % 8 == 0 -> bijective. (R1->R2 evidence: FETCH 303 MB -> 22 MB.)
  const int blk = ((blockIdx.x & 7) << 7) | (blockIdx.x >> 3);
  const int b = blk >> 9;
  const int h = (blk >> 4) & 31;
  const int w0 = (blk & 15) << 1;  // two w positions: w0, w0+1

  const int lane = tid & 63;
  const int wv = tid >> 6;  // wave 0..3 = D-tiles (T0,s0),(T1,s0),(T1,s1),(T2,s1)
  const int jb = (wv == 0) ? 0 : (wv == 3) ? 32 : 16;  // A-tile j base
  const int db = (wv >= 2) ? 16 : 0;                   // d-strip base
  const int l15 = lane & 15;
  const int lhi = lane >> 4;

  const float* in1b = in1 + ((size_t)b << 21);
  const float* in2b = in2 + ((size_t)b << 21);

  // zero halo rows of both column buffers (j<4, j>=36): written once, never touched again
  for (int i = tid; i < 1152; i += 256) {
    const int bu = i / 576;
    const int r = i - bu * 576;
    const int jrow = r / 36;
    const int cc = r - jrow * 36;
    const int j = (jrow < 4) ? jrow : jrow + 32;
    h2 z = {(__fp16)0.f, (__fp16)0.f};
    *(h2*)&colbuf[bu][j * JSTR + cc * 2] = z;
  }

  // staging role: d = tid&31 (coalesced), c-quad = tid>>5
  const int sd = tid & 31;
  const int scq = tid >> 5;

  auto stage = [&](const float* src, bool valid, __fp16* dst) {
#pragma unroll
    for (int it = 0; it < 4; ++it) {
      const int cp = scq + (it << 3);  // c-pair 0..31
      h2 v = {(__fp16)0.f, (__fp16)0.f};
      if (valid) {
        const float x = src[((size_t)(2 * cp) << 15) + sd];
        const float y = src[((size_t)(2 * cp + 1) << 15) + sd];
        v = __builtin_amdgcn_cvt_pkrtz(x, y);
      }
      *(h2*)&dst[(4 + sd) * JSTR + 2 * cp] = v;  // [j=4+d][c] layout
    }
  };

  // ---- prologue: load in1 B-operand fragments (per wave: its d-strip, 2 c-halves, 2 pos)
  h8 bfr[2][2];
#pragma unroll
  for (int pos = 0; pos < 2; ++pos) {
    __syncthreads();
    stage(in1b + (h << 10) + ((w0 + pos) << 5), true, colbuf[0]);
    __syncthreads();
#pragma unroll
    for (int ch = 0; ch < 2; ++ch)
      bfr[pos][ch] =
          *(const h8*)&colbuf[0][(4 + db + l15) * JSTR + ch * 32 + (lhi << 3)];
  }
  __syncthreads();
  // stage in2 column 0 into buf 0
  {
    const int hp = h - 4, wp = w0 - 4;
    const bool valid = ((unsigned)hp < 32u) && ((unsigned)wp < 32u);
    stage(in2b + (hp << 10) + (wp << 5), valid, colbuf[0]);
  }
  __syncthreads();

  // band-write targets per (lane, reg): m=(lhi*4+r), n=l15; j=jb+m, d=db+n, dz=j-d
  int boff[4];
  unsigned bmask = 0;
#pragma unroll
  for (int r = 0; r < 4; ++r) {
    const int m = (lhi << 2) + r;
    const int dz = jb + m - db - l15;
    if ((unsigned)dz < 9u) bmask |= 1u << r;
    boff[r] = dz * 32 + db + l15;
  }

  // ---- main loop over 90 columns (hc 0..8, wc 0..9), ONE barrier per column
  for (int ci = 0; ci < 90; ++ci) {
    // (1) issue next-column loads into registers (consumed at step 5)
    float lx[4], ly[4];
    bool nvalid = false;
    if (ci + 1 < 90) {
      const int cn = ci + 1;
      const int hcn = cn / 10;
      const int wcn = cn - hcn * 10;
      const int hp = h - 4 + hcn;
      const int wp = w0 - 4 + wcn;
      nvalid = ((unsigned)hp < 32u) && ((unsigned)wp < 32u);
      if (nvalid) {
        const float* src = in2b + (hp << 10) + (wp << 5);
#pragma unroll
        for (int it = 0; it < 4; ++it) {
          const int cp = scq + (it << 3);
          lx[it] = src[((size_t)(2 * cp) << 15) + sd];
          ly[it] = src[((size_t)(2 * cp + 1) << 15) + sd];
        }
      }
    }

    // (2,3) compute column ci, band-write into obuf[ci&1]
    const int hc = ci / 10;
    const int wc = ci - hc * 10;
    const bool serve[2] = {wc <= 8, wc >= 1};  // dx = wc - pos must be in [0,9)

    const __fp16* cb = colbuf[ci & 1];
    float* ob = obuf[ci & 1];
    const h8 a0 = *(const h8*)&cb[(jb + l15) * JSTR + (lhi << 3)];
    const h8 a1 = *(const h8*)&cb[(jb + l15) * JSTR + 32 + (lhi << 3)];
#pragma unroll
    for (int pos = 0; pos < 2; ++pos) {
      if (serve[pos]) {
        f4 acc = {0.f, 0.f, 0.f, 0.f};
        acc = __builtin_amdgcn_mfma_f32_16x16x32_f16(a0, bfr[pos][0], acc, 0, 0, 0);
        acc = __builtin_amdgcn_mfma_f32_16x16x32_f16(a1, bfr[pos][1], acc, 0, 0, 0);
#pragma unroll
        for (int r = 0; r < 4; ++r)
          if (bmask & (1u << r)) ob[pos * 288 + boff[r]] = acc[r];
      }
    }

    // (4) readback column ci-1 from obuf[(ci-1)&1] (visible since last barrier)
    if (ci > 0 && tid < 144) {
      const int cprev = ci - 1;
      const int hcp = cprev / 10;
      const int wcp = cprev - hcp * 10;
      const int pos = tid >= 72;
      const int rr = tid - pos * 72;
      const int dz = rr >> 3;
      const int q = rr & 7;
      const bool sv = pos ? (wcp >= 1) : (wcp <= 8);
      if (sv) {
        const f4 v = *(const f4*)&obuf[cprev & 1][pos * 288 + dz * 32 + (q << 2)];
        const size_t ch = (size_t)(b * 729 + (hcp * 9 + (wcp - pos)) * 9 + dz);
        f4* dstp = (f4*)(out + (ch << 15) + (h << 10) + ((w0 + pos) << 5) + (q << 2));
        __builtin_nontemporal_store(v, dstp);
      }
    }

    // (5) write staged column ci+1 into colbuf[(ci+1)&1] (vmcnt wait lands here,
    // load latency hidden under steps 2-4)
    if (ci + 1 < 90) {
#pragma unroll
      for (int it = 0; it < 4; ++it) {
        const int cp = scq + (it << 3);
        h2 v = {(__fp16)0.f, (__fp16)0.f};
        if (nvalid) v = __builtin_amdgcn_cvt_pkrtz(lx[it], ly[it]);
        *(h2*)&colbuf[(ci + 1) & 1][(4 + sd) * JSTR + 2 * cp] = v;
      }
    }

    __syncthreads();  // the single per-column barrier
  }

  // ---- epilogue: readback last column (ci=89: hc=8, wc=9 -> only pos=1 served)
  if (tid >= 72 && tid < 144) {
    const int rr = tid - 72;
    const int dz = rr >> 3;
    const int q = rr & 7;
    const f4 v = *(const f4*)&obuf[1][288 + dz * 32 + (q << 2)];
    const size_t ch = (size_t)(b * 729 + (8 * 9 + 8) * 9 + dz);
    f4* dstp = (f4*)(out + (ch << 15) + (h << 10) + ((w0 + 1) << 5) + (q << 2));
    __builtin_nontemporal_store(v, dstp);
  }
}

extern "C" void kernel_launch(void* const* d_in, const int* in_sizes, int n_in,
                              void* d_out, int out_size, void* d_ws, size_t ws_size,
                              hipStream_t stream) {
  const float* in1 = (const float*)d_in[0];
  const float* in2 = (const float*)d_in[1];
  float* out = (float*)d_out;
  corr3d_mfma<<<dim3(1024), dim3(256), 0, stream>>>(in1, in2, out);
}

// Round 5
// 253.344 us; speedup vs baseline: 1.1295x; 1.1047x over previous
//
#include <hip/hip_runtime.h>

typedef __fp16 h2 __attribute__((ext_vector_type(2)));
typedef __fp16 h8 __attribute__((ext_vector_type(8)));
typedef float f4 __attribute__((ext_vector_type(4)));

namespace {
constexpr int JSTR = 72;         // halves per j-row (64 c + 8 pad) -> 144 B, breaks bank aliasing
constexpr int JN = 48;           // j rows; j<4 and j>=36 are permanent zero halo
constexpr int COLH = JN * JSTR;  // 3456 halves = 6912 B per column buffer
}

// R5: occupancy doubling. R2/R4 evidence: no pipe >half busy (Mfma 7%, VALU 15%,
// HBM 20%, Occ 35%) at 4 blocks/CU -> latency-bound, under-provisioned TLP.
// Split each (b,h,w0) tile's 90-column chain across TWO blocks (ci 0..44 /
// 45..89, mid-hc split keeps output coverage exact & disjoint): grid 2048,
// __launch_bounds__(256,8) -> 8 blocks/CU = 32 waves/CU, serial chain halved.
// LDS 18.4KB x 8 = 147KB <= 160KB; VGPR 28 <= 64 so 8 waves/SIMD fit.
//
// Pipeline per column (ONE barrier, from R4):
//   1. issue next-column global loads -> regs        (T14 issue-early)
//   2. ds_read A-frags, MFMA column ci
//   3. band-write acc -> obuf[ci&1]                  (obuf double-buffered)
//   4. readback column ci-1 from obuf[(ci-1)&1] -> global NT stores
//   5. cvt + ds_write staged regs -> colbuf[(ci+1)&1] (T14 write-late)
//   6. __syncthreads
__global__ __launch_bounds__(256, 8) void corr3d_mfma(
    const float* __restrict__ in1, const float* __restrict__ in2,
    float* __restrict__ out)
{
  __shared__ __align__(16) __fp16 colbuf[2][COLH];     // 13824 B
  __shared__ __align__(16) float obuf[2][2 * 9 * 32];  // [parity][pos*288+dz*32+d], 4608 B

  const int tid = threadIdx.x;
  // XCD-aware chunked swizzle: blocks sharing in2 are consecutive logical ids
  // (same h: 2 halves x adjacent wb); 2048 % 8 == 0 -> bijective, 256/XCD slab
  // spans 8 h-rows -> in2 slice ~4.5 MB, L2-resident (R2 evidence: FETCH
  // 303 MB -> 22 MB from this remap family).
  const int blk = ((blockIdx.x & 7) << 8) | (blockIdx.x >> 3);
  const int half = blk & 1;             // column-range half
  const int w0 = ((blk >> 1) & 15) << 1;  // two w positions: w0, w0+1
  const int h = (blk >> 5) & 31;
  const int b = blk >> 10;
  const int ciLo = half ? 45 : 0;
  const int ciHi = half ? 90 : 45;

  const int lane = tid & 63;
  const int wv = tid >> 6;  // wave 0..3 = D-tiles (T0,s0),(T1,s0),(T1,s1),(T2,s1)
  const int jb = (wv == 0) ? 0 : (wv == 3) ? 32 : 16;  // A-tile j base
  const int db = (wv >= 2) ? 16 : 0;                   // d-strip base
  const int l15 = lane & 15;
  const int lhi = lane >> 4;

  const float* in1b = in1 + ((size_t)b << 21);
  const float* in2b = in2 + ((size_t)b << 21);

  // zero halo rows of both column buffers (j<4, j>=36): written once, never touched again
  for (int i = tid; i < 1152; i += 256) {
    const int bu = i / 576;
    const int r = i - bu * 576;
    const int jrow = r / 36;
    const int cc = r - jrow * 36;
    const int j = (jrow < 4) ? jrow : jrow + 32;
    h2 z = {(__fp16)0.f, (__fp16)0.f};
    *(h2*)&colbuf[bu][j * JSTR + cc * 2] = z;
  }

  // staging role: d = tid&31 (coalesced), c-quad = tid>>5
  const int sd = tid & 31;
  const int scq = tid >> 5;

  auto stage = [&](const float* src, bool valid, __fp16* dst) {
#pragma unroll
    for (int it = 0; it < 4; ++it) {
      const int cp = scq + (it << 3);  // c-pair 0..31
      h2 v = {(__fp16)0.f, (__fp16)0.f};
      if (valid) {
        const float x = src[((size_t)(2 * cp) << 15) + sd];
        const float y = src[((size_t)(2 * cp + 1) << 15) + sd];
        v = __builtin_amdgcn_cvt_pkrtz(x, y);
      }
      *(h2*)&dst[(4 + sd) * JSTR + 2 * cp] = v;  // [j=4+d][c] layout
    }
  };

  // ---- prologue: load in1 B-operand fragments (per wave: its d-strip, 2 c-halves, 2 pos)
  h8 bfr[2][2];
#pragma unroll
  for (int pos = 0; pos < 2; ++pos) {
    __syncthreads();
    stage(in1b + (h << 10) + ((w0 + pos) << 5), true, colbuf[0]);
    __syncthreads();
#pragma unroll
    for (int ch = 0; ch < 2; ++ch)
      bfr[pos][ch] =
          *(const h8*)&colbuf[0][(4 + db + l15) * JSTR + ch * 32 + (lhi << 3)];
  }
  __syncthreads();
  // stage first in2 column (ciLo) into colbuf[ciLo&1]
  {
    const int hcn = ciLo / 10;
    const int wcn = ciLo - hcn * 10;
    const int hp = h - 4 + hcn, wp = w0 - 4 + wcn;
    const bool valid = ((unsigned)hp < 32u) && ((unsigned)wp < 32u);
    stage(in2b + (hp << 10) + (wp << 5), valid, colbuf[ciLo & 1]);
  }
  __syncthreads();

  // band-write targets per (lane, reg): m=(lhi*4+r), n=l15; j=jb+m, d=db+n, dz=j-d
  int boff[4];
  unsigned bmask = 0;
#pragma unroll
  for (int r = 0; r < 4; ++r) {
    const int m = (lhi << 2) + r;
    const int dz = jb + m - db - l15;
    if ((unsigned)dz < 9u) bmask |= 1u << r;
    boff[r] = dz * 32 + db + l15;
  }

  // ---- main loop over this block's column range, ONE barrier per column
  for (int ci = ciLo; ci < ciHi; ++ci) {
    // (1) issue next-column loads into registers (consumed at step 5)
    float lx[4], ly[4];
    bool nvalid = false;
    if (ci + 1 < ciHi) {
      const int cn = ci + 1;
      const int hcn = cn / 10;
      const int wcn = cn - hcn * 10;
      const int hp = h - 4 + hcn;
      const int wp = w0 - 4 + wcn;
      nvalid = ((unsigned)hp < 32u) && ((unsigned)wp < 32u);
      if (nvalid) {
        const float* src = in2b + (hp << 10) + (wp << 5);
#pragma unroll
        for (int it = 0; it < 4; ++it) {
          const int cp = scq + (it << 3);
          lx[it] = src[((size_t)(2 * cp) << 15) + sd];
          ly[it] = src[((size_t)(2 * cp + 1) << 15) + sd];
        }
      }
    }

    // (2,3) compute column ci, band-write into obuf[ci&1]
    const int hc = ci / 10;
    const int wc = ci - hc * 10;
    const bool serve[2] = {wc <= 8, wc >= 1};  // dx = wc - pos must be in [0,9)

    const __fp16* cb = colbuf[ci & 1];
    float* ob = obuf[ci & 1];
    const h8 a0 = *(const h8*)&cb[(jb + l15) * JSTR + (lhi << 3)];
    const h8 a1 = *(const h8*)&cb[(jb + l15) * JSTR + 32 + (lhi << 3)];
#pragma unroll
    for (int pos = 0; pos < 2; ++pos) {
      if (serve[pos]) {
        f4 acc = {0.f, 0.f, 0.f, 0.f};
        acc = __builtin_amdgcn_mfma_f32_16x16x32_f16(a0, bfr[pos][0], acc, 0, 0, 0);
        acc = __builtin_amdgcn_mfma_f32_16x16x32_f16(a1, bfr[pos][1], acc, 0, 0, 0);
#pragma unroll
        for (int r = 0; r < 4; ++r)
          if (bmask & (1u << r)) ob[pos * 288 + boff[r]] = acc[r];
      }
    }

    // (4) readback column ci-1 from obuf[(ci-1)&1] (visible since last barrier)
    if (ci > ciLo && tid < 144) {
      const int cprev = ci - 1;
      const int hcp = cprev / 10;
      const int wcp = cprev - hcp * 10;
      const int pos = tid >= 72;
      const int rr = tid - pos * 72;
      const int dz = rr >> 3;
      const int q = rr & 7;
      const bool sv = pos ? (wcp >= 1) : (wcp <= 8);
      if (sv) {
        const f4 v = *(const f4*)&obuf[cprev & 1][pos * 288 + dz * 32 + (q << 2)];
        const size_t ch = (size_t)(b * 729 + (hcp * 9 + (wcp - pos)) * 9 + dz);
        f4* dstp = (f4*)(out + (ch << 15) + (h << 10) + ((w0 + pos) << 5) + (q << 2));
        __builtin_nontemporal_store(v, dstp);
      }
    }

    // (5) write staged column ci+1 into colbuf[(ci+1)&1] (vmcnt wait lands here,
    // load latency hidden under steps 2-4)
    if (ci + 1 < ciHi) {
#pragma unroll
      for (int it = 0; it < 4; ++it) {
        const int cp = scq + (it << 3);
        h2 v = {(__fp16)0.f, (__fp16)0.f};
        if (nvalid) v = __builtin_amdgcn_cvt_pkrtz(lx[it], ly[it]);
        *(h2*)&colbuf[(ci + 1) & 1][(4 + sd) * JSTR + 2 * cp] = v;
      }
    }

    __syncthreads();  // the single per-column barrier
  }

  // ---- epilogue: readback this range's last column (general: both pos checked)
  {
    const int cl = ciHi - 1;
    const int hcp = cl / 10;
    const int wcp = cl - hcp * 10;
    if (tid < 144) {
      const int pos = tid >= 72;
      const int rr = tid - pos * 72;
      const int dz = rr >> 3;
      const int q = rr & 7;
      const bool sv = pos ? (wcp >= 1) : (wcp <= 8);
      if (sv) {
        const f4 v = *(const f4*)&obuf[cl & 1][pos * 288 + dz * 32 + (q << 2)];
        const size_t ch = (size_t)(b * 729 + (hcp * 9 + (wcp - pos)) * 9 + dz);
        f4* dstp = (f4*)(out + (ch << 15) + (h << 10) + ((w0 + pos) << 5) + (q << 2));
        __builtin_nontemporal_store(v, dstp);
      }
    }
  }
}

extern "C" void kernel_launch(void* const* d_in, const int* in_sizes, int n_in,
                              void* d_out, int out_size, void* d_ws, size_t ws_size,
                              hipStream_t stream) {
  const float* in1 = (const float*)d_in[0];
  const float* in2 = (const float*)d_in[1];
  float* out = (float*)d_out;
  corr3d_mfma<<<dim3(2048), dim3(256), 0, stream>>>(in1, in2, out);
}

// Round 7
// 248.434 us; speedup vs baseline: 1.1518x; 1.0198x over previous
//
#include <hip/hip_runtime.h>

typedef __fp16 h2 __attribute__((ext_vector_type(2)));
typedef __fp16 h8 __attribute__((ext_vector_type(8)));
typedef float f4 __attribute__((ext_vector_type(4)));

namespace {
constexpr int JSTR = 72;          // halves per j-row (64 c + 8 pad) -> 144 B, breaks bank aliasing
constexpr int JROWS = 40;         // j = d+dz in [0,40): rows 40-47 of the old 48-row layout were NEVER
                                  // referenced by a valid (dz<9) output, so they are dropped. wv3's b128
                                  // reads at rows 40-47 now read adjacent LDS (finite garbage); they feed
                                  // only C rows m>=8 which the dz-mask provably never writes
                                  // (wv3: dz=16+m-l15<9 requires l15>=m+8 -> m<=7; MFMA C-row m depends
                                  // only on A-row m, held by lanes l15==m).
constexpr int COLH = JROWS * JSTR;  // 2880 halves = 5760 B per column buffer
}

// R6 (resubmit; prior run was a container-infra failure, not a kernel failure):
// 4 positions per staged column at unchanged block shape (256 thr, 4 waves).
// R5 evidence: 32 waves/CU is the hard cap and nothing is pipe-bound -> the cost
// is block-column rounds/CU (360). Serving w0..w0+3 per column cuts rounds to
// 216 and amortizes A-frag LDS reads (read once, used by all 4 pos), staging,
// and global loads by ~40% per output. R2's 4-pos failure was a TLP confound
// (512-thr blocks, 16 waves/CU), not the amortization.
// LDS 20736 B -> 7 blocks/CU = 28 waves/CU.
//
// Pipeline per column (ONE barrier, from R4):
//   1. issue next-column global loads -> regs        (T14 issue-early)
//   2. ds_read A-frags (once), MFMA x 4 pos
//   3. band-write acc -> obuf[ci&1]                  (obuf double-buffered)
//   4. readback column ci-1 from obuf[(ci-1)&1] -> global NT stores
//   5. cvt + ds_write staged regs -> colbuf[(ci+1)&1] (T14 write-late)
//   6. __syncthreads
__global__ __launch_bounds__(256, 7) void corr3d_mfma(
    const float* __restrict__ in1, const float* __restrict__ in2,
    float* __restrict__ out)
{
  __shared__ __align__(16) __fp16 colbuf[2][COLH];    // 11520 B
  __shared__ __align__(16) float obuf[2][4 * 288];    // [parity][pos*288+dz*32+d], 9216 B

  const int tid = threadIdx.x;
  // XCD-aware chunked swizzle: blocks sharing in2 are consecutive logical ids;
  // 2048 % 8 == 0 -> bijective, 256-block slab/XCD spans 8 h-rows (same
  // locality as R5, which measured FETCH 303 MB -> 22 MB).
  const int blk = ((blockIdx.x & 7) << 8) | (blockIdx.x >> 3);
  const int quarter = blk & 3;            // column-range quarter
  const int w0 = ((blk >> 2) & 7) << 2;   // four w positions: w0 .. w0+3
  const int h = (blk >> 5) & 31;
  const int b = blk >> 10;
  const int ciLo = quarter * 27;
  const int ciHi = ciLo + 27;             // 108 columns (9 hc x 12 wc) split x4

  const int lane = tid & 63;
  const int wv = tid >> 6;  // wave 0..3 = D-tiles (T0,s0),(T1,s0),(T1,s1),(T2,s1)
  const int jb = (wv == 0) ? 0 : (wv == 3) ? 32 : 16;  // A-tile j base
  const int db = (wv >= 2) ? 16 : 0;                   // d-strip base
  const int l15 = lane & 15;
  const int lhi = lane >> 4;

  const float* in1b = in1 + ((size_t)b << 21);
  const float* in2b = in2 + ((size_t)b << 21);

  // zero halo rows of both column buffers (j<4, j>=36): written once, never touched again
  for (int i = tid; i < 576; i += 256) {
    const int bu = i / 288;
    const int r = i - bu * 288;
    const int jrow = r / 36;
    const int cc = r - jrow * 36;
    const int j = (jrow < 4) ? jrow : jrow + 32;  // rows 0-3, 36-39
    h2 z = {(__fp16)0.f, (__fp16)0.f};
    *(h2*)&colbuf[bu][j * JSTR + cc * 2] = z;
  }

  // staging role: d = tid&31 (coalesced), c-quad = tid>>5
  const int sd = tid & 31;
  const int scq = tid >> 5;

  auto stage = [&](const float* src, bool valid, __fp16* dst) {
#pragma unroll
    for (int it = 0; it < 4; ++it) {
      const int cp = scq + (it << 3);  // c-pair 0..31
      h2 v = {(__fp16)0.f, (__fp16)0.f};
      if (valid) {
        const float x = src[((size_t)(2 * cp) << 15) + sd];
        const float y = src[((size_t)(2 * cp + 1) << 15) + sd];
        v = __builtin_amdgcn_cvt_pkrtz(x, y);
      }
      *(h2*)&dst[(4 + sd) * JSTR + 2 * cp] = v;  // [j=4+d][c] layout, rows 4..35
    }
  };

  // ---- prologue: in1 B-operand fragments for all 4 positions (static bfr indices)
  h8 bfr[4][2];
#pragma unroll
  for (int pos = 0; pos < 4; ++pos) {
    __syncthreads();
    stage(in1b + (h << 10) + ((w0 + pos) << 5), true, colbuf[0]);
    __syncthreads();
#pragma unroll
    for (int ch = 0; ch < 2; ++ch)
      bfr[pos][ch] =
          *(const h8*)&colbuf[0][(4 + db + l15) * JSTR + ch * 32 + (lhi << 3)];
  }
  __syncthreads();
  // stage first in2 column (ciLo) into colbuf[ciLo&1]
  {
    const int hcn = ciLo / 12;
    const int wcn = ciLo - hcn * 12;
    const int hp = h - 4 + hcn, wp = w0 - 4 + wcn;
    const bool valid = ((unsigned)hp < 32u) && ((unsigned)wp < 32u);
    stage(in2b + (hp << 10) + (wp << 5), valid, colbuf[ciLo & 1]);
  }
  __syncthreads();

  // band-write constants: m=(lhi*4+r), dz = jb+m-db-l15 = mr+r; off = dz*32+db+l15
  const int mr = jb - db + (lhi << 2) - l15;
  const int dzb = db + l15;

  // ---- main loop over this block's 27 columns, ONE barrier per column
  for (int ci = ciLo; ci < ciHi; ++ci) {
    // (1) issue next-column loads into registers (consumed at step 5)
    float lx[4], ly[4];
    bool nvalid = false;
    if (ci + 1 < ciHi) {
      const int cn = ci + 1;
      const int hcn = cn / 12;
      const int wcn = cn - hcn * 12;
      const int hp = h - 4 + hcn;
      const int wp = w0 - 4 + wcn;
      nvalid = ((unsigned)hp < 32u) && ((unsigned)wp < 32u);
      if (nvalid) {
        const float* src = in2b + (hp << 10) + (wp << 5);
#pragma unroll
        for (int it = 0; it < 4; ++it) {
          const int cp = scq + (it << 3);
          lx[it] = src[((size_t)(2 * cp) << 15) + sd];
          ly[it] = src[((size_t)(2 * cp + 1) << 15) + sd];
        }
      }
    }

    // (2,3) compute column ci for all 4 positions, band-write into obuf[ci&1]
    const int hc = ci / 12;
    const int wc = ci - hc * 12;

    const __fp16* cb = colbuf[ci & 1];
    float* ob = obuf[ci & 1];
    const h8 a0 = *(const h8*)&cb[(jb + l15) * JSTR + (lhi << 3)];
    const h8 a1 = *(const h8*)&cb[(jb + l15) * JSTR + 32 + (lhi << 3)];
#pragma unroll
    for (int pos = 0; pos < 4; ++pos) {
      if ((unsigned)(wc - pos) <= 8u) {  // dx = wc - pos in [0,9)
        f4 acc = {0.f, 0.f, 0.f, 0.f};
        acc = __builtin_amdgcn_mfma_f32_16x16x32_f16(a0, bfr[pos][0], acc, 0, 0, 0);
        acc = __builtin_amdgcn_mfma_f32_16x16x32_f16(a1, bfr[pos][1], acc, 0, 0, 0);
#pragma unroll
        for (int r = 0; r < 4; ++r) {
          const int dz = mr + r;
          if ((unsigned)dz < 9u) ob[pos * 288 + dz * 32 + dzb] = acc[r];
        }
      }
    }

    // (4) readback column ci-1 from obuf[(ci-1)&1]: 288 slots over 256 threads
    if (ci > ciLo) {
      const int cprev = ci - 1;
      const int hcp = cprev / 12;
      const int wcp = cprev - hcp * 12;
      const float* op = obuf[cprev & 1];
      for (int s = tid; s < 288; s += 256) {
        const int pos = s / 72;
        const int rr = s - pos * 72;
        const int dz = rr >> 3;
        const int q = rr & 7;
        if ((unsigned)(wcp - pos) <= 8u) {
          const f4 v = *(const f4*)&op[pos * 288 + dz * 32 + (q << 2)];
          const size_t chn = (size_t)(b * 729 + (hcp * 9 + (wcp - pos)) * 9 + dz);
          f4* dstp = (f4*)(out + (chn << 15) + (h << 10) + ((w0 + pos) << 5) + (q << 2));
          __builtin_nontemporal_store(v, dstp);
        }
      }
    }

    // (5) write staged column ci+1 into colbuf[(ci+1)&1] (vmcnt wait lands here)
    if (ci + 1 < ciHi) {
#pragma unroll
      for (int it = 0; it < 4; ++it) {
        const int cp = scq + (it << 3);
        h2 v = {(__fp16)0.f, (__fp16)0.f};
        if (nvalid) v = __builtin_amdgcn_cvt_pkrtz(lx[it], ly[it]);
        *(h2*)&colbuf[(ci + 1) & 1][(4 + sd) * JSTR + 2 * cp] = v;
      }
    }

    __syncthreads();  // the single per-column barrier
  }

  // ---- epilogue: readback this range's last column
  {
    const int cl = ciHi - 1;
    const int hcp = cl / 12;
    const int wcp = cl - hcp * 12;
    const float* op = obuf[cl & 1];
    for (int s = tid; s < 288; s += 256) {
      const int pos = s / 72;
      const int rr = s - pos * 72;
      const int dz = rr >> 3;
      const int q = rr & 7;
      if ((unsigned)(wcp - pos) <= 8u) {
        const f4 v = *(const f4*)&op[pos * 288 + dz * 32 + (q << 2)];
        const size_t chn = (size_t)(b * 729 + (hcp * 9 + (wcp - pos)) * 9 + dz);
        f4* dstp = (f4*)(out + (chn << 15) + (h << 10) + ((w0 + pos) << 5) + (q << 2));
        __builtin_nontemporal_store(v, dstp);
      }
    }
  }
}

extern "C" void kernel_launch(void* const* d_in, const int* in_sizes, int n_in,
                              void* d_out, int out_size, void* d_ws, size_t ws_size,
                              hipStream_t stream) {
  const float* in1 = (const float*)d_in[0];
  const float* in2 = (const float*)d_in[1];
  float* out = (float*)d_out;
  corr3d_mfma<<<dim3(2048), dim3(256), 0, stream>>>(in1, in2, out);
}